// Round 5
// baseline (322.004 us; speedup 1.0000x reference)
//
#include <hip/hip_runtime.h>
#include <hip/hip_bf16.h>

// Problem constants
#define B_ 8
#define S_ 4096
#define H_ 512

using short8 = __attribute__((ext_vector_type(8))) short;
using f32x4  = __attribute__((ext_vector_type(4))) float;

// ---------- helpers ----------
__device__ __forceinline__ float bf2f(unsigned u16) {
    return __uint_as_float(u16 << 16);
}
__device__ __forceinline__ unsigned pk2bf(float x, float y) {
    __hip_bfloat162 h = __float22bfloat162_rn(make_float2(x, y));  // v_cvt_pk_bf16_f32
    return *reinterpret_cast<unsigned*>(&h);
}
__device__ __forceinline__ float softplus_f(float x) {
    float sp = __logf(1.0f + __expf(x));
    return x > 15.0f ? x : sp;
}

// async global->LDS, 16B per lane; LDS dest = wave-uniform base + lane*16
typedef __attribute__((address_space(1))) void* gbl_ptr_t;
typedef __attribute__((address_space(3))) void* lds_ptr_t;
__device__ __forceinline__ void gload_lds16(const void* g, void* l) {
    __builtin_amdgcn_global_load_lds((gbl_ptr_t)g, (lds_ptr_t)l, 16, 0, 0);
}

// raw barrier (no vmcnt/lgkmcnt drain) with compiler memory fences
#define BAR() do { asm volatile("" ::: "memory"); \
                   __builtin_amdgcn_s_barrier(); \
                   asm volatile("" ::: "memory"); } while (0)

// lgkmcnt(0) wait + scheduling fence (rule #18: MFMA is register-only and
// hipcc will hoist it past an asm waitcnt unless sched_barrier(0) follows)
#define WAIT_LGKM0() do { asm volatile("s_waitcnt lgkmcnt(0)" ::: "memory"); \
                          __builtin_amdgcn_sched_barrier(0); } while (0)

// ---------- Pass 1: one-shot fp32 -> bf16 conversion of A (lstm) and W ----------
#define ASZ8 2097152u   // A elems / 8
#define TOT8 2162688u   // (A + W elems) / 8

__global__ __launch_bounds__(256)
void convert_bf16(const float* __restrict__ A, const float* __restrict__ Wm,
                  uint4* __restrict__ Ab, uint4* __restrict__ Wb) {
    for (unsigned i = blockIdx.x * 256u + threadIdx.x; i < TOT8; i += 2048u * 256u) {
        const float4* src; uint4* dst; unsigned off;
        if (i < ASZ8) { src = (const float4*)A;  dst = Ab; off = i; }
        else          { src = (const float4*)Wm; dst = Wb; off = i - ASZ8; }
        float4 a = src[2u * off], b = src[2u * off + 1u];
        uint4 o;
        o.x = pk2bf(a.x, a.y); o.y = pk2bf(a.z, a.w);
        o.z = pk2bf(b.x, b.y); o.w = pk2bf(b.z, b.w);
        dst[off] = o;
    }
}

// ---------- Pass 2: 128x128 bf16 GEMM, BK=32 2-slot ring, 5 blocks/CU ----------
// Round-4 post-mortem: MfmaUtil 22%, Occupancy 19% -- 64 KB LDS capped us at
// 2 blocks/CU; the matrix pipe idles because only 2 waves/SIMD cover stalls.
// This round: BK 64->32 halves the ring to 32 KB -> 5 blocks/CU (VGPR 88 also
// allows 5 waves/SIMD). Same counted-vmcnt ring (lookahead 1 slice, vmcnt(4),
// never 0 until tail), same wave geometry / B q,r remap / epilogue as round 4.
// BK=32 swizzle: s(row) = (row + (row>>2)) & 3. Staging lane (lane&3) sources
// granule (lane&3)^s; read of logical granule l4 uses slot l4^s. s is invariant
// under row+16 and row+64 -> all fragment/issue strides are compile-time.
// Bank check (per 16-lane quarter): slot8 = 4*(row&1) + (l4^s) hits each of 8
// 16B-slots exactly 2x -> 2-way aliasing = free (m136).
#define TM 128
#define TN 128
#define BK 32

__global__ __launch_bounds__(256, 5)
void gemm_softplus(const unsigned short* __restrict__ Ab,
                   const unsigned short* __restrict__ Wb,
                   const float* __restrict__ bias,
                   unsigned* __restrict__ QR) {
    __shared__ unsigned short As[2][4096];   // 2 slots x (128 rows x 32 bf16) = 16 KB
    __shared__ unsigned short Bs[2][4096];   // 16 KB   (total 32 KB -> 5 blocks/CU)

    // XCD-chunked swizzle: 2048 blocks = 8 XCD * 256; the 8 blocks sharing an
    // A strip land on ONE XCD (round-1/4 measured: FETCH 265 -> 22 MB).
    const int bid     = blockIdx.x;
    const int logical = (bid & 7) * 256 + (bid >> 3);
    const int bm = logical >> 3;     // 0..255
    const int bn = logical & 7;      // 0..7

    const int t    = threadIdx.x;
    const int wave = t >> 6;
    const int lane = t & 63;
    const int wm  = (wave >> 1) * 64;
    const int wn  = (wave & 1) * 64;
    const int l15 = lane & 15;
    const int l4  = lane >> 4;

    const int m0 = bm * TM;

    // ---- staging geometry (linear LDS dest, inverse-swizzled global source) ----
    // issue i (0,1) covers tile rows i*64 + wave*16 + (lane>>2); lane writes the
    // 16B granule (lane&3) of its row. Source granule = (lane&3) ^ s_st where
    // s_st = ((lane>>2) + (lane>>4)) & 3  (i*64, wave*16 vanish mod 4).
    const int lr2  = lane >> 2;                        // 0..15
    const int s_st = (lr2 + (lane >> 4)) & 3;
    const int sg   = ((lane & 3) ^ s_st) * 8;          // source k offset (elems)
    const int row0 = wave * 16 + lr2;                  // tile row, issue 0 (A)
    // B tile row -> W row: rows 0..31 -> q cols bn*64+0..31, 32..63 -> same +512
    // (r), 64..95 -> q +32, 96..127 -> r +32 (enables packed {q,r} epilogue).
    const int nr0 = bn * 64 + (row0 & 31) + ((row0 & 64) >> 1) + ((row0 & 32) << 4);
    // issue 1 strides: A rows +64; B cols +32 (q->q+32 / r->r+32), s unchanged.
    const unsigned short* ag0 = Ab + (size_t)(m0 + row0) * 512 + sg;
    const unsigned short* bg0 = Wb + (size_t)nr0 * 512 + sg;
    const unsigned short* ag1 = ag0 + (size_t)64 * 512;
    const unsigned short* bg1 = bg0 + (size_t)32 * 512;
    const int sd0 = wave * 512;          // LDS dest (elems), wave-uniform
    const int sd1 = sd0 + 2048;          // issue 1: +64 rows * 32 elems

    // ---- ds_read geometry (swizzled read matches staged content) ----
    // fragment row = wm/wn + i*16 + l15; s(row) = (l15 + (l15>>2)) & 3 for all
    // wm/wn/i (invariant mod 4). Logical granule l4 -> physical slot l4 ^ s.
    const int s_rd = (l15 + (l15 >> 2)) & 3;
    const int gsw  = (l4 ^ s_rd) * 8;
    const int aoff = (wm + l15) * 32 + gsw;   // + i*512 per fragment (compile-time)
    const int boff = (wn + l15) * 32 + gsw;

    f32x4 acc[4][4] = {};

#define STAGE(s) do { \
    const int _sl = (s) & 1; const int _kc = (s) * BK; \
    gload_lds16(ag0 + _kc, &As[_sl][sd0]); \
    gload_lds16(ag1 + _kc, &As[_sl][sd1]); \
    gload_lds16(bg0 + _kc, &Bs[_sl][sd0]); \
    gload_lds16(bg1 + _kc, &Bs[_sl][sd1]); \
} while (0)

#define SLICE(g, VMN, DOSTG) do { \
    const unsigned short* _a = &As[(g) & 1][0]; \
    const unsigned short* _b = &Bs[(g) & 1][0]; \
    if (DOSTG) STAGE((g) + 1); \
    asm volatile("s_waitcnt vmcnt(" #VMN ")" ::: "memory"); \
    BAR(); \
    short8 af[4], bf[4]; \
    _Pragma("unroll") for (int i = 0; i < 4; ++i) { \
        af[i] = *(const short8*)(_a + aoff + i * 512); \
        bf[i] = *(const short8*)(_b + boff + i * 512); \
    } \
    WAIT_LGKM0(); \
    __builtin_amdgcn_s_setprio(1); \
    _Pragma("unroll") for (int i = 0; i < 4; ++i) \
    _Pragma("unroll") for (int j = 0; j < 4; ++j) \
        acc[i][j] = __builtin_amdgcn_mfma_f32_16x16x32_bf16(af[i], bf[j], acc[i][j], 0, 0, 0); \
    __builtin_amdgcn_s_setprio(0); \
    BAR(); \
} while (0)

    STAGE(0);                                   // 4 loads in flight
    for (int g = 0; g < 15; ++g) {
        SLICE(g, 4, 1);                         // stage g+1; wait slice g only
    }
    SLICE(15, 0, 0);                            // tail: full drain is free

#undef SLICE
#undef STAGE

    // epilogue (rounds 1/4 verified): bias + softplus, packed {q,r} 4B stores
#pragma unroll
    for (int j = 0; j < 2; ++j) {
        const int h  = bn * 64 + (wn >> 1) + j * 16 + l15;  // 0..511
        const float bq = bias[h];
        const float br = bias[h + 512];
#pragma unroll
        for (int i = 0; i < 4; ++i) {
            const int mb = m0 + wm + i * 16 + l4 * 4;
#pragma unroll
            for (int r = 0; r < 4; ++r) {
                const float qv = softplus_f(acc[i][j][r] + bq);
                const float rv = softplus_f(acc[i][j + 2][r] + br);
                QR[(size_t)(mb + r) * 512 + h] = pk2bf(qv, rv);
            }
        }
    }
}

// ---------- Pass 3: chunked Kalman scan (unchanged from round 4) ----------
// 32 chunks of 128 steps, 64-step warm-up. 1 h-column/thread, 8-buffer
// rotation, prefetch depth 4 groups. ng in {16,24} -> unguarded COMP.
#define CHUNK 128
#define WARM 64

__global__ __launch_bounds__(256, 2)
void kalman_scan(const float* __restrict__ z,
                 const unsigned* __restrict__ QR,
                 float* __restrict__ out) {
    const int t     = threadIdx.x;
    const int hb    = blockIdx.x & 1;
    const int b     = (blockIdx.x >> 1) & 7;
    const int chunk = blockIdx.x >> 4;          // 0..31
    const int h     = hb * 256 + t;             // 0..511
    const int s0    = chunk << 7;               // chunk*128
    const int sw    = (chunk == 0) ? 0 : (s0 - WARM);
    const size_t base = ((size_t)(b * S_ + sw)) * 512 + h;

    const float*    zp  = z + base;             // stride 512 floats / step
    const unsigned* qrp = (const unsigned*)QR + base;
    float*          op  = out + base;

    const int ng    = ((s0 + CHUNK) - sw) >> 3;   // 16 (chunk 0) or 24
    const int skipg = (s0 - sw) >> 3;             // 0 or 8

    float    Z0[8], Z1[8], Z2[8], Z3[8], Z4[8], Z5[8], Z6[8], Z7[8];
    unsigned Q0[8], Q1[8], Q2[8], Q3[8], Q4[8], Q5[8], Q6[8], Q7[8];

#define LOADG(g, Zb, Qb) { const int _o = (g) * 8;                          \
    _Pragma("unroll") for (int u = 0; u < 8; ++u) {                         \
        Zb[u] = zp[(size_t)(_o + u) * 512]; Qb[u] = qrp[(size_t)(_o + u) * 512]; } }

#define COMP(g, Zb, Qb) { const int _o = (g) * 8; const bool _st = (g) >= skipg; \
    _Pragma("unroll") for (int u = 0; u < 8; ++u) {                         \
        const float q  = bf2f(Qb[u] & 0xffffu);                             \
        const float r  = bf2f(Qb[u] >> 16);                                 \
        const float Pp = P + q, rr = r + 1e-6f;                             \
        const float K  = Pp * __builtin_amdgcn_rcpf(Pp + rr);               \
        state = fmaf(K, Zb[u] - state, state); P = rr * K;                  \
        if (_st) op[(size_t)(_o + u) * 512] = state; } }

    LOADG(0, Z0, Q0); LOADG(1, Z1, Q1); LOADG(2, Z2, Q2); LOADG(3, Z3, Q3);

    float state = Z0[0];   // state init = z[sw]
    float P = 0.1f;

    for (int g = 0; g < ng; g += 8) {
        if (g + 4  < ng) LOADG(g + 4,  Z4, Q4); COMP(g,     Z0, Q0);
        if (g + 5  < ng) LOADG(g + 5,  Z5, Q5); COMP(g + 1, Z1, Q1);
        if (g + 6  < ng) LOADG(g + 6,  Z6, Q6); COMP(g + 2, Z2, Q2);
        if (g + 7  < ng) LOADG(g + 7,  Z7, Q7); COMP(g + 3, Z3, Q3);
        if (g + 8  < ng) LOADG(g + 8,  Z0, Q0); COMP(g + 4, Z4, Q4);
        if (g + 9  < ng) LOADG(g + 9,  Z1, Q1); COMP(g + 5, Z5, Q5);
        if (g + 10 < ng) LOADG(g + 10, Z2, Q2); COMP(g + 6, Z6, Q6);
        if (g + 11 < ng) LOADG(g + 11, Z3, Q3); COMP(g + 7, Z7, Q7);
    }
#undef LOADG
#undef COMP
}

extern "C" void kernel_launch(void* const* d_in, const int* in_sizes, int n_in,
                              void* d_out, int out_size, void* d_ws, size_t ws_size,
                              hipStream_t stream) {
    const float* lstm = (const float*)d_in[0];   // (8,4096,512) fp32
    const float* Wm   = (const float*)d_in[1];   // (1024,512)  fp32
    const float* bias = (const float*)d_in[2];   // (1024,)     fp32

    unsigned* QRw = (unsigned*)d_ws;             // packed {q,r} bf16x2, 64 MB

    // d_out (64 MB) is dead until the scan writes it -> bf16 scratch:
    // Ab = 32 MB at offset 0, Wb = 1 MB at offset 32 MB.
    unsigned short* Abf = (unsigned short*)d_out;
    unsigned short* Wbf = (unsigned short*)((char*)d_out + (32u << 20));

    hipLaunchKernelGGL(convert_bf16, dim3(2048), dim3(256), 0, stream,
                       lstm, Wm, (uint4*)Abf, (uint4*)Wbf);

    // 256 M-tiles x 8 N-tiles = 2048 blocks of 256 threads (5 blocks/CU)
    hipLaunchKernelGGL(gemm_softplus, dim3(2048), dim3(256), 0, stream,
                       Abf, Wbf, bias, QRw);

    // 2 h-halves * 8 batches * 32 chunks = 512 blocks of 256 threads (2/CU)
    hipLaunchKernelGGL(kalman_scan, dim3(512), dim3(256), 0, stream,
                       lstm, QRw, (float*)d_out);
}

// Round 6
// 204.021 us; speedup vs baseline: 1.5783x; 1.5783x over previous
//
#include <hip/hip_runtime.h>
#include <hip/hip_bf16.h>

// Problem constants
#define B_ 8
#define S_ 4096
#define H_ 512

using short8 = __attribute__((ext_vector_type(8))) short;
using f32x4  = __attribute__((ext_vector_type(4))) float;

// ---------- helpers ----------
__device__ __forceinline__ float bf2f(unsigned u16) {
    return __uint_as_float(u16 << 16);
}
__device__ __forceinline__ unsigned pk2bf(float x, float y) {
    __hip_bfloat162 h = __float22bfloat162_rn(make_float2(x, y));  // v_cvt_pk_bf16_f32
    return *reinterpret_cast<unsigned*>(&h);
}
__device__ __forceinline__ float softplus_f(float x) {
    float sp = __logf(1.0f + __expf(x));
    return x > 15.0f ? x : sp;
}

// async global->LDS, 16B per lane; LDS dest = wave-uniform base + lane*16
typedef __attribute__((address_space(1))) void* gbl_ptr_t;
typedef __attribute__((address_space(3))) void* lds_ptr_t;
__device__ __forceinline__ void gload_lds16(const void* g, void* l) {
    __builtin_amdgcn_global_load_lds((gbl_ptr_t)g, (lds_ptr_t)l, 16, 0, 0);
}

// raw barrier (no vmcnt/lgkmcnt drain) with compiler memory fences
#define BAR() do { asm volatile("" ::: "memory"); \
                   __builtin_amdgcn_s_barrier(); \
                   asm volatile("" ::: "memory"); } while (0)

// lgkmcnt(0) wait + scheduling fence (rule #18: MFMA is register-only and
// hipcc will hoist it past an asm waitcnt unless sched_barrier(0) follows)
#define WAIT_LGKM0() do { asm volatile("s_waitcnt lgkmcnt(0)" ::: "memory"); \
                          __builtin_amdgcn_sched_barrier(0); } while (0)

// ---------- Pass 1: one-shot fp32 -> bf16 conversion of A (lstm) and W ----------
#define ASZ8 2097152u   // A elems / 8
#define TOT8 2162688u   // (A + W elems) / 8

__global__ __launch_bounds__(256)
void convert_bf16(const float* __restrict__ A, const float* __restrict__ Wm,
                  uint4* __restrict__ Ab, uint4* __restrict__ Wb) {
    for (unsigned i = blockIdx.x * 256u + threadIdx.x; i < TOT8; i += 2048u * 256u) {
        const float4* src; uint4* dst; unsigned off;
        if (i < ASZ8) { src = (const float4*)A;  dst = Ab; off = i; }
        else          { src = (const float4*)Wm; dst = Wb; off = i - ASZ8; }
        float4 a = src[2u * off], b = src[2u * off + 1u];
        uint4 o;
        o.x = pk2bf(a.x, a.y); o.y = pk2bf(a.z, a.w);
        o.z = pk2bf(b.x, b.y); o.w = pk2bf(b.z, b.w);
        dst[off] = o;
    }
}

// ---------- Pass 2: 128x128 bf16 GEMM, BK=32 2-slot ring, 4 blocks/CU ----------
// Round-5 post-mortem: __launch_bounds__(256,5) forced VGPR<=64 (occupancy
// tiers step at 64/128/256), but f32x4 acc[4][4] alone needs 64 VGPRs ->
// accumulators spilled to scratch (VGPR 48, WRITE_SIZE 503 MB, 195 us).
// Fix: bounds (256,4). Compiler returns to ~88 VGPR (round-4 proven, no
// spill); VGPR tier 65..128 gives 4 waves/SIMD; 32 KB LDS allows 5 blocks/CU
// -> residency = 4 blocks/CU, 2x round-4's. All geometry identical to r5:
//   staging: issue i covers rows i*64 + wave*16 + (lane>>2), lane writes 16B
//   granule (lane&3); content swizzle s(row) = (row + (row>>2)) & 3, source
//   granule (lane&3)^s, read slot l4^s; s invariant under row+16/row+64.
//   Counted-vmcnt ring: stage g+1 before compute g, vmcnt(4), never 0 in loop.
#define TM 128
#define TN 128
#define BK 32

__global__ __launch_bounds__(256, 4)
void gemm_softplus(const unsigned short* __restrict__ Ab,
                   const unsigned short* __restrict__ Wb,
                   const float* __restrict__ bias,
                   unsigned* __restrict__ QR) {
    __shared__ unsigned short As[2][4096];   // 2 slots x (128 rows x 32 bf16) = 16 KB
    __shared__ unsigned short Bs[2][4096];   // 16 KB   (total 32 KB)

    // XCD-chunked swizzle: 2048 blocks = 8 XCD * 256; the 8 blocks sharing an
    // A strip land on ONE XCD (round-1/4 measured: FETCH 265 -> 22 MB).
    const int bid     = blockIdx.x;
    const int logical = (bid & 7) * 256 + (bid >> 3);
    const int bm = logical >> 3;     // 0..255
    const int bn = logical & 7;      // 0..7

    const int t    = threadIdx.x;
    const int wave = t >> 6;
    const int lane = t & 63;
    const int wm  = (wave >> 1) * 64;
    const int wn  = (wave & 1) * 64;
    const int l15 = lane & 15;
    const int l4  = lane >> 4;

    const int m0 = bm * TM;

    // ---- staging geometry (linear LDS dest, inverse-swizzled global source) ----
    const int lr2  = lane >> 2;                        // 0..15
    const int s_st = (lr2 + (lane >> 4)) & 3;
    const int sg   = ((lane & 3) ^ s_st) * 8;          // source k offset (elems)
    const int row0 = wave * 16 + lr2;                  // tile row, issue 0 (A)
    // B tile row -> W row: rows 0..31 -> q cols bn*64+0..31, 32..63 -> same +512
    // (r), 64..95 -> q +32, 96..127 -> r +32 (enables packed {q,r} epilogue).
    const int nr0 = bn * 64 + (row0 & 31) + ((row0 & 64) >> 1) + ((row0 & 32) << 4);
    const unsigned short* ag0 = Ab + (size_t)(m0 + row0) * 512 + sg;
    const unsigned short* bg0 = Wb + (size_t)nr0 * 512 + sg;
    const unsigned short* ag1 = ag0 + (size_t)64 * 512;   // issue 1: A rows +64
    const unsigned short* bg1 = bg0 + (size_t)32 * 512;   // issue 1: B cols +32
    const int sd0 = wave * 512;          // LDS dest (elems), wave-uniform
    const int sd1 = sd0 + 2048;          // issue 1: +64 rows * 32 elems

    // ---- ds_read geometry (swizzled read matches staged content) ----
    const int s_rd = (l15 + (l15 >> 2)) & 3;
    const int gsw  = (l4 ^ s_rd) * 8;
    const int aoff = (wm + l15) * 32 + gsw;   // + i*512 per fragment (compile-time)
    const int boff = (wn + l15) * 32 + gsw;

    f32x4 acc[4][4] = {};

#define STAGE(s) do { \
    const int _sl = (s) & 1; const int _kc = (s) * BK; \
    gload_lds16(ag0 + _kc, &As[_sl][sd0]); \
    gload_lds16(ag1 + _kc, &As[_sl][sd1]); \
    gload_lds16(bg0 + _kc, &Bs[_sl][sd0]); \
    gload_lds16(bg1 + _kc, &Bs[_sl][sd1]); \
} while (0)

#define SLICE(g, VMN, DOSTG) do { \
    const unsigned short* _a = &As[(g) & 1][0]; \
    const unsigned short* _b = &Bs[(g) & 1][0]; \
    if (DOSTG) STAGE((g) + 1); \
    asm volatile("s_waitcnt vmcnt(" #VMN ")" ::: "memory"); \
    BAR(); \
    short8 af[4], bf[4]; \
    _Pragma("unroll") for (int i = 0; i < 4; ++i) { \
        af[i] = *(const short8*)(_a + aoff + i * 512); \
        bf[i] = *(const short8*)(_b + boff + i * 512); \
    } \
    WAIT_LGKM0(); \
    __builtin_amdgcn_s_setprio(1); \
    _Pragma("unroll") for (int i = 0; i < 4; ++i) \
    _Pragma("unroll") for (int j = 0; j < 4; ++j) \
        acc[i][j] = __builtin_amdgcn_mfma_f32_16x16x32_bf16(af[i], bf[j], acc[i][j], 0, 0, 0); \
    __builtin_amdgcn_s_setprio(0); \
    BAR(); \
} while (0)

    STAGE(0);                                   // 4 loads in flight
    for (int g = 0; g < 15; ++g) {
        SLICE(g, 4, 1);                         // stage g+1; wait slice g only
    }
    SLICE(15, 0, 0);                            // tail: full drain is free

#undef SLICE
#undef STAGE

    // epilogue (rounds 1/4 verified): bias + softplus, packed {q,r} 4B stores
#pragma unroll
    for (int j = 0; j < 2; ++j) {
        const int h  = bn * 64 + (wn >> 1) + j * 16 + l15;  // 0..511
        const float bq = bias[h];
        const float br = bias[h + 512];
#pragma unroll
        for (int i = 0; i < 4; ++i) {
            const int mb = m0 + wm + i * 16 + l4 * 4;
#pragma unroll
            for (int r = 0; r < 4; ++r) {
                const float qv = softplus_f(acc[i][j][r] + bq);
                const float rv = softplus_f(acc[i][j + 2][r] + br);
                QR[(size_t)(mb + r) * 512 + h] = pk2bf(qv, rv);
            }
        }
    }
}

// ---------- Pass 3: chunked Kalman scan (unchanged from rounds 4/5) ----------
// 32 chunks of 128 steps, 64-step warm-up. 1 h-column/thread, 8-buffer
// rotation, prefetch depth 4 groups. ng in {16,24} -> unguarded COMP.
#define CHUNK 128
#define WARM 64

__global__ __launch_bounds__(256, 2)
void kalman_scan(const float* __restrict__ z,
                 const unsigned* __restrict__ QR,
                 float* __restrict__ out) {
    const int t     = threadIdx.x;
    const int hb    = blockIdx.x & 1;
    const int b     = (blockIdx.x >> 1) & 7;
    const int chunk = blockIdx.x >> 4;          // 0..31
    const int h     = hb * 256 + t;             // 0..511
    const int s0    = chunk << 7;               // chunk*128
    const int sw    = (chunk == 0) ? 0 : (s0 - WARM);
    const size_t base = ((size_t)(b * S_ + sw)) * 512 + h;

    const float*    zp  = z + base;             // stride 512 floats / step
    const unsigned* qrp = (const unsigned*)QR + base;
    float*          op  = out + base;

    const int ng    = ((s0 + CHUNK) - sw) >> 3;   // 16 (chunk 0) or 24
    const int skipg = (s0 - sw) >> 3;             // 0 or 8

    float    Z0[8], Z1[8], Z2[8], Z3[8], Z4[8], Z5[8], Z6[8], Z7[8];
    unsigned Q0[8], Q1[8], Q2[8], Q3[8], Q4[8], Q5[8], Q6[8], Q7[8];

#define LOADG(g, Zb, Qb) { const int _o = (g) * 8;                          \
    _Pragma("unroll") for (int u = 0; u < 8; ++u) {                         \
        Zb[u] = zp[(size_t)(_o + u) * 512]; Qb[u] = qrp[(size_t)(_o + u) * 512]; } }

#define COMP(g, Zb, Qb) { const int _o = (g) * 8; const bool _st = (g) >= skipg; \
    _Pragma("unroll") for (int u = 0; u < 8; ++u) {                         \
        const float q  = bf2f(Qb[u] & 0xffffu);                             \
        const float r  = bf2f(Qb[u] >> 16);                                 \
        const float Pp = P + q, rr = r + 1e-6f;                             \
        const float K  = Pp * __builtin_amdgcn_rcpf(Pp + rr);               \
        state = fmaf(K, Zb[u] - state, state); P = rr * K;                  \
        if (_st) op[(size_t)(_o + u) * 512] = state; } }

    LOADG(0, Z0, Q0); LOADG(1, Z1, Q1); LOADG(2, Z2, Q2); LOADG(3, Z3, Q3);

    float state = Z0[0];   // state init = z[sw]
    float P = 0.1f;

    for (int g = 0; g < ng; g += 8) {
        if (g + 4  < ng) LOADG(g + 4,  Z4, Q4); COMP(g,     Z0, Q0);
        if (g + 5  < ng) LOADG(g + 5,  Z5, Q5); COMP(g + 1, Z1, Q1);
        if (g + 6  < ng) LOADG(g + 6,  Z6, Q6); COMP(g + 2, Z2, Q2);
        if (g + 7  < ng) LOADG(g + 7,  Z7, Q7); COMP(g + 3, Z3, Q3);
        if (g + 8  < ng) LOADG(g + 8,  Z0, Q0); COMP(g + 4, Z4, Q4);
        if (g + 9  < ng) LOADG(g + 9,  Z1, Q1); COMP(g + 5, Z5, Q5);
        if (g + 10 < ng) LOADG(g + 10, Z2, Q2); COMP(g + 6, Z6, Q6);
        if (g + 11 < ng) LOADG(g + 11, Z3, Q3); COMP(g + 7, Z7, Q7);
    }
#undef LOADG
#undef COMP
}

extern "C" void kernel_launch(void* const* d_in, const int* in_sizes, int n_in,
                              void* d_out, int out_size, void* d_ws, size_t ws_size,
                              hipStream_t stream) {
    const float* lstm = (const float*)d_in[0];   // (8,4096,512) fp32
    const float* Wm   = (const float*)d_in[1];   // (1024,512)  fp32
    const float* bias = (const float*)d_in[2];   // (1024,)     fp32

    unsigned* QRw = (unsigned*)d_ws;             // packed {q,r} bf16x2, 64 MB

    // d_out (64 MB) is dead until the scan writes it -> bf16 scratch:
    // Ab = 32 MB at offset 0, Wb = 1 MB at offset 32 MB.
    unsigned short* Abf = (unsigned short*)d_out;
    unsigned short* Wbf = (unsigned short*)((char*)d_out + (32u << 20));

    hipLaunchKernelGGL(convert_bf16, dim3(2048), dim3(256), 0, stream,
                       lstm, Wm, (uint4*)Abf, (uint4*)Wbf);

    // 256 M-tiles x 8 N-tiles = 2048 blocks of 256 threads (4 blocks/CU)
    hipLaunchKernelGGL(gemm_softplus, dim3(2048), dim3(256), 0, stream,
                       Abf, Wbf, bias, QRw);

    // 2 h-halves * 8 batches * 32 chunks = 512 blocks of 256 threads (2/CU)
    hipLaunchKernelGGL(kalman_scan, dim3(512), dim3(256), 0, stream,
                       lstm, QRw, (float*)d_out);
}

// Round 7
// 203.671 us; speedup vs baseline: 1.5810x; 1.0017x over previous
//
#include <hip/hip_runtime.h>
#include <hip/hip_bf16.h>

// Problem constants
#define B_ 8
#define S_ 4096
#define H_ 512

using short8 = __attribute__((ext_vector_type(8))) short;
using f32x4  = __attribute__((ext_vector_type(4))) float;

// ---------- helpers ----------
__device__ __forceinline__ float bf2f(unsigned u16) {
    return __uint_as_float(u16 << 16);
}
__device__ __forceinline__ unsigned pk2bf(float x, float y) {
    __hip_bfloat162 h = __float22bfloat162_rn(make_float2(x, y));  // v_cvt_pk_bf16_f32
    return *reinterpret_cast<unsigned*>(&h);
}
__device__ __forceinline__ float softplus_f(float x) {
    float sp = __logf(1.0f + __expf(x));
    return x > 15.0f ? x : sp;
}

// async global->LDS, 16B per lane; LDS dest = wave-uniform base + lane*16
typedef __attribute__((address_space(1))) void* gbl_ptr_t;
typedef __attribute__((address_space(3))) void* lds_ptr_t;
__device__ __forceinline__ void gload_lds16(const void* g, void* l) {
    __builtin_amdgcn_global_load_lds((gbl_ptr_t)g, (lds_ptr_t)l, 16, 0, 0);
}

// raw barrier (no vmcnt/lgkmcnt drain) with compiler memory fences.
// Plain LDS loads cannot cross the "memory"-clobbered asm -> read/write
// ordering around slot reuse is enforced; MFMA (register-only) may move,
// which is harmless: it consumes registers, not LDS.
#define BAR() do { asm volatile("" ::: "memory"); \
                   __builtin_amdgcn_s_barrier(); \
                   asm volatile("" ::: "memory"); } while (0)

// ---------- Pass 1: one-shot fp32 -> bf16 conversion of A (lstm) and W ----------
#define ASZ8 2097152u   // A elems / 8
#define TOT8 2162688u   // (A + W elems) / 8

__global__ __launch_bounds__(256)
void convert_bf16(const float* __restrict__ A, const float* __restrict__ Wm,
                  uint4* __restrict__ Ab, uint4* __restrict__ Wb) {
    for (unsigned i = blockIdx.x * 256u + threadIdx.x; i < TOT8; i += 2048u * 256u) {
        const float4* src; uint4* dst; unsigned off;
        if (i < ASZ8) { src = (const float4*)A;  dst = Ab; off = i; }
        else          { src = (const float4*)Wm; dst = Wb; off = i - ASZ8; }
        float4 a = src[2u * off], b = src[2u * off + 1u];
        uint4 o;
        o.x = pk2bf(a.x, a.y); o.y = pk2bf(a.z, a.w);
        o.z = pk2bf(b.x, b.y); o.w = pk2bf(b.z, b.w);
        dst[off] = o;
    }
}

// ---------- Pass 2: 128x128 bf16 GEMM, BK=32 4-slot ring, DEPTH-3 pipeline ----
// Round-6 post-mortem: occupancy 19->33% gave ZERO gain; 588 TF = the
// documented 2-phase ceiling (m233: stage+wait+barrier dominates). Binding
// constraints were (1) depth-1 lookahead (issue-to-wait ~300 cyc < load
// latency) and (2) forced lgkmcnt(0)+sched_barrier serializing reads->MFMA
// (unneeded: ds_reads here are plain loads; the compiler emits fine-grained
// lgkmcnt itself, m97). This round: 4-slot ring (64 KB = static-LDS limit;
// 128 KB was rounds-2/3's crash), STAGE(g+3) while computing g, steady
// vmcnt(12) = 3 slices in flight (~900 cyc coverage), no forced lgkm waits.
// Geometry (staging swizzle, B q/r remap, ds_read swizzle, epilogue) is
// byte-identical to rounds 4/5/6 (correctness-proven).
#define TM 128
#define TN 128
#define BK 32

__global__ __launch_bounds__(256, 2)
void gemm_softplus(const unsigned short* __restrict__ Ab,
                   const unsigned short* __restrict__ Wb,
                   const float* __restrict__ bias,
                   unsigned* __restrict__ QR) {
    __shared__ unsigned short As[4][4096];   // 4 slots x (128 rows x 32 bf16) = 32 KB
    __shared__ unsigned short Bs[4][4096];   // 32 KB  (total 64 KB static = limit)

    // XCD-chunked swizzle: 2048 blocks = 8 XCD * 256; the 8 blocks sharing an
    // A strip land on ONE XCD (measured: FETCH 265 -> 22 MB).
    const int bid     = blockIdx.x;
    const int logical = (bid & 7) * 256 + (bid >> 3);
    const int bm = logical >> 3;     // 0..255
    const int bn = logical & 7;      // 0..7

    const int t    = threadIdx.x;
    const int wave = t >> 6;
    const int lane = t & 63;
    const int wm  = (wave >> 1) * 64;
    const int wn  = (wave & 1) * 64;
    const int l15 = lane & 15;
    const int l4  = lane >> 4;

    const int m0 = bm * TM;

    // ---- staging geometry (linear LDS dest, inverse-swizzled global source) ----
    // issue i (0,1) covers tile rows i*64 + wave*16 + (lane>>2); lane writes the
    // 16B granule (lane&3) of its row. Content swizzle s(row)=(row+(row>>2))&3:
    // source granule (lane&3)^s; s invariant under row+16 / row+64.
    const int lr2  = lane >> 2;                        // 0..15
    const int s_st = (lr2 + (lane >> 4)) & 3;
    const int sg   = ((lane & 3) ^ s_st) * 8;          // source k offset (elems)
    const int row0 = wave * 16 + lr2;                  // tile row, issue 0 (A)
    // B tile row -> W row: rows 0..31 -> q cols bn*64+0..31, 32..63 -> same +512
    // (r), 64..95 -> q +32, 96..127 -> r +32 (enables packed {q,r} epilogue).
    const int nr0 = bn * 64 + (row0 & 31) + ((row0 & 64) >> 1) + ((row0 & 32) << 4);
    const unsigned short* ag0 = Ab + (size_t)(m0 + row0) * 512 + sg;
    const unsigned short* bg0 = Wb + (size_t)nr0 * 512 + sg;
    const unsigned short* ag1 = ag0 + (size_t)64 * 512;   // issue 1: A rows +64
    const unsigned short* bg1 = bg0 + (size_t)32 * 512;   // issue 1: B cols +32
    const int sd0 = wave * 512;          // LDS dest (elems), wave-uniform
    const int sd1 = sd0 + 2048;          // issue 1: +64 rows * 32 elems

    // ---- ds_read geometry (swizzled read matches staged content) ----
    const int s_rd = (l15 + (l15 >> 2)) & 3;
    const int gsw  = (l4 ^ s_rd) * 8;
    const int aoff = (wm + l15) * 32 + gsw;   // + i*512 per fragment (compile-time)
    const int boff = (wn + l15) * 32 + gsw;

    f32x4 acc[4][4] = {};

#define STAGE(s) do { \
    const int _sl = (s) & 3; const int _kc = (s) * BK; \
    gload_lds16(ag0 + _kc, &As[_sl][sd0]); \
    gload_lds16(ag1 + _kc, &As[_sl][sd1]); \
    gload_lds16(bg0 + _kc, &Bs[_sl][sd0]); \
    gload_lds16(bg1 + _kc, &Bs[_sl][sd1]); \
} while (0)

// Per slice: stage g+3 (slot (g-1)&3, freed by slice-(g-1)'s end barrier) ->
// counted vmcnt (slice g's 4 loads done; 12 = 3 slices stay in flight) ->
// barrier (all 4 waves' loads landed) -> plain ds_reads + MFMA (compiler
// interleaves with its own fine-grained lgkmcnt) -> end barrier (licenses
// the NEXT slice's STAGE to overwrite slot (g+1-1)&3... i.e. slot reuse).
#define SLICE(g, VMN, DOSTG) do { \
    const unsigned short* _a = &As[(g) & 3][0]; \
    const unsigned short* _b = &Bs[(g) & 3][0]; \
    if (DOSTG) STAGE((g) + 3); \
    asm volatile("s_waitcnt vmcnt(" #VMN ")" ::: "memory"); \
    BAR(); \
    short8 af[4], bf[4]; \
    _Pragma("unroll") for (int i = 0; i < 4; ++i) { \
        af[i] = *(const short8*)(_a + aoff + i * 512); \
        bf[i] = *(const short8*)(_b + boff + i * 512); \
    } \
    __builtin_amdgcn_s_setprio(1); \
    _Pragma("unroll") for (int i = 0; i < 4; ++i) \
    _Pragma("unroll") for (int j = 0; j < 4; ++j) \
        acc[i][j] = __builtin_amdgcn_mfma_f32_16x16x32_bf16(af[i], bf[j], acc[i][j], 0, 0, 0); \
    __builtin_amdgcn_s_setprio(0); \
    BAR(); \
} while (0)

    // prologue: fill slots 0..2 (12 loads in flight)
    STAGE(0); STAGE(1); STAGE(2);

    // main: 13 slices, 3-slice lookahead, vmcnt(12) steady state
    for (int g = 0; g < 13; ++g) SLICE(g, 12, 1);
    // drain: outstanding 12 -> 8 -> 4 -> 0
    SLICE(13, 8, 0);
    SLICE(14, 4, 0);
    SLICE(15, 0, 0);

#undef SLICE
#undef STAGE

    // epilogue (rounds 1/4/6 verified): bias + softplus, packed {q,r} 4B stores
#pragma unroll
    for (int j = 0; j < 2; ++j) {
        const int h  = bn * 64 + (wn >> 1) + j * 16 + l15;  // 0..511
        const float bq = bias[h];
        const float br = bias[h + 512];
#pragma unroll
        for (int i = 0; i < 4; ++i) {
            const int mb = m0 + wm + i * 16 + l4 * 4;
#pragma unroll
            for (int r = 0; r < 4; ++r) {
                const float qv = softplus_f(acc[i][j][r] + bq);
                const float rv = softplus_f(acc[i][j + 2][r] + br);
                QR[(size_t)(mb + r) * 512 + h] = pk2bf(qv, rv);
            }
        }
    }
}

// ---------- Pass 3: chunked Kalman scan (unchanged from rounds 4/5/6) ----------
// 32 chunks of 128 steps, 64-step warm-up. 1 h-column/thread, 8-buffer
// rotation, prefetch depth 4 groups. ng in {16,24} -> unguarded COMP.
#define CHUNK 128
#define WARM 64

__global__ __launch_bounds__(256, 2)
void kalman_scan(const float* __restrict__ z,
                 const unsigned* __restrict__ QR,
                 float* __restrict__ out) {
    const int t     = threadIdx.x;
    const int hb    = blockIdx.x & 1;
    const int b     = (blockIdx.x >> 1) & 7;
    const int chunk = blockIdx.x >> 4;          // 0..31
    const int h     = hb * 256 + t;             // 0..511
    const int s0    = chunk << 7;               // chunk*128
    const int sw    = (chunk == 0) ? 0 : (s0 - WARM);
    const size_t base = ((size_t)(b * S_ + sw)) * 512 + h;

    const float*    zp  = z + base;             // stride 512 floats / step
    const unsigned* qrp = (const unsigned*)QR + base;
    float*          op  = out + base;

    const int ng    = ((s0 + CHUNK) - sw) >> 3;   // 16 (chunk 0) or 24
    const int skipg = (s0 - sw) >> 3;             // 0 or 8

    float    Z0[8], Z1[8], Z2[8], Z3[8], Z4[8], Z5[8], Z6[8], Z7[8];
    unsigned Q0[8], Q1[8], Q2[8], Q3[8], Q4[8], Q5[8], Q6[8], Q7[8];

#define LOADG(g, Zb, Qb) { const int _o = (g) * 8;                          \
    _Pragma("unroll") for (int u = 0; u < 8; ++u) {                         \
        Zb[u] = zp[(size_t)(_o + u) * 512]; Qb[u] = qrp[(size_t)(_o + u) * 512]; } }

#define COMP(g, Zb, Qb) { const int _o = (g) * 8; const bool _st = (g) >= skipg; \
    _Pragma("unroll") for (int u = 0; u < 8; ++u) {                         \
        const float q  = bf2f(Qb[u] & 0xffffu);                             \
        const float r  = bf2f(Qb[u] >> 16);                                 \
        const float Pp = P + q, rr = r + 1e-6f;                             \
        const float K  = Pp * __builtin_amdgcn_rcpf(Pp + rr);               \
        state = fmaf(K, Zb[u] - state, state); P = rr * K;                  \
        if (_st) op[(size_t)(_o + u) * 512] = state; } }

    LOADG(0, Z0, Q0); LOADG(1, Z1, Q1); LOADG(2, Z2, Q2); LOADG(3, Z3, Q3);

    float state = Z0[0];   // state init = z[sw]
    float P = 0.1f;

    for (int g = 0; g < ng; g += 8) {
        if (g + 4  < ng) LOADG(g + 4,  Z4, Q4); COMP(g,     Z0, Q0);
        if (g + 5  < ng) LOADG(g + 5,  Z5, Q5); COMP(g + 1, Z1, Q1);
        if (g + 6  < ng) LOADG(g + 6,  Z6, Q6); COMP(g + 2, Z2, Q2);
        if (g + 7  < ng) LOADG(g + 7,  Z7, Q7); COMP(g + 3, Z3, Q3);
        if (g + 8  < ng) LOADG(g + 8,  Z0, Q0); COMP(g + 4, Z4, Q4);
        if (g + 9  < ng) LOADG(g + 9,  Z1, Q1); COMP(g + 5, Z5, Q5);
        if (g + 10 < ng) LOADG(g + 10, Z2, Q2); COMP(g + 6, Z6, Q6);
        if (g + 11 < ng) LOADG(g + 11, Z3, Q3); COMP(g + 7, Z7, Q7);
    }
#undef LOADG
#undef COMP
}

extern "C" void kernel_launch(void* const* d_in, const int* in_sizes, int n_in,
                              void* d_out, int out_size, void* d_ws, size_t ws_size,
                              hipStream_t stream) {
    const float* lstm = (const float*)d_in[0];   // (8,4096,512) fp32
    const float* Wm   = (const float*)d_in[1];   // (1024,512)  fp32
    const float* bias = (const float*)d_in[2];   // (1024,)     fp32

    unsigned* QRw = (unsigned*)d_ws;             // packed {q,r} bf16x2, 64 MB

    // d_out (64 MB) is dead until the scan writes it -> bf16 scratch:
    // Ab = 32 MB at offset 0, Wb = 1 MB at offset 32 MB.
    unsigned short* Abf = (unsigned short*)d_out;
    unsigned short* Wbf = (unsigned short*)((char*)d_out + (32u << 20));

    hipLaunchKernelGGL(convert_bf16, dim3(2048), dim3(256), 0, stream,
                       lstm, Wm, (uint4*)Abf, (uint4*)Wbf);

    // 256 M-tiles x 8 N-tiles = 2048 blocks of 256 threads (2 blocks/CU)
    hipLaunchKernelGGL(gemm_softplus, dim3(2048), dim3(256), 0, stream,
                       Abf, Wbf, bias, QRw);

    // 2 h-halves * 8 batches * 32 chunks = 512 blocks of 256 threads (2/CU)
    hipLaunchKernelGGL(kalman_scan, dim3(512), dim3(256), 0, stream,
                       lstm, QRw, (float*)d_out);
}

// Round 8
// 201.599 us; speedup vs baseline: 1.5972x; 1.0103x over previous
//
#include <hip/hip_runtime.h>
#include <hip/hip_bf16.h>

// Problem constants
#define B_ 8
#define S_ 4096
#define H_ 512

using short8 = __attribute__((ext_vector_type(8))) short;
using f32x4  = __attribute__((ext_vector_type(4))) float;

// ---------- helpers ----------
__device__ __forceinline__ float bf2f(unsigned u16) {
    return __uint_as_float(u16 << 16);
}
__device__ __forceinline__ unsigned pk2bf(float x, float y) {
    __hip_bfloat162 h = __float22bfloat162_rn(make_float2(x, y));  // v_cvt_pk_bf16_f32
    return *reinterpret_cast<unsigned*>(&h);
}
__device__ __forceinline__ float softplus_f(float x) {
    float sp = __logf(1.0f + __expf(x));
    return x > 15.0f ? x : sp;
}

// async global->LDS, 16B per lane; LDS dest = wave-uniform base + lane*16
typedef __attribute__((address_space(1))) void* gbl_ptr_t;
typedef __attribute__((address_space(3))) void* lds_ptr_t;
__device__ __forceinline__ void gload_lds16(const void* g, void* l) {
    __builtin_amdgcn_global_load_lds((gbl_ptr_t)g, (lds_ptr_t)l, 16, 0, 0);
}

// raw barrier (no vmcnt/lgkmcnt drain) with compiler memory fences
#define BAR() do { asm volatile("" ::: "memory"); \
                   __builtin_amdgcn_s_barrier(); \
                   asm volatile("" ::: "memory"); } while (0)

// ---------- Pass 1: one-shot fp32 -> bf16 conversion of A (lstm) and W ----------
// Round-8 fix: FULLY CONTIGUOUS. Old version had thread i load src[2i] and
// src[2i+1] (32 B lane stride -> 2x L1/L2 transactions per instruction, wave
// span 4 KB half-used per instruction). Now thread i loads ONE float4 at flat
// index i (64 lanes x 16 B = 1 KB contiguous per instruction) and stores ONE
// uint2 (512 B/wave contiguous). Wb sits immediately after Ab in d_out, so a
// single contiguous uint2 destination covers A then W.
#define ASZ4 4194304u   // A float4 count (16,777,216 floats)
#define TOT4 4325376u   // A + W float4 count

__global__ __launch_bounds__(256)
void convert_bf16(const float* __restrict__ A, const float* __restrict__ Wm,
                  uint2* __restrict__ dst) {
    for (unsigned i = blockIdx.x * 256u + threadIdx.x; i < TOT4; i += 2048u * 256u) {
        const float4* p = (i < ASZ4) ? ((const float4*)A) + i
                                     : ((const float4*)Wm) + (i - ASZ4);
        const float4 v = *p;
        uint2 o;
        o.x = pk2bf(v.x, v.y);
        o.y = pk2bf(v.z, v.w);
        dst[i] = o;
    }
}

// ---------- Pass 2: 128x128 bf16 GEMM, BK=32 2-slot ring, 4 blocks/CU ----------
// Round-6 config, byte-identical: the measured best (58.5 us, MfmaUtil 22.7%).
// Round-7's depth-3/64KB variant REGRESSED to 84 us (occupancy fell to 2
// blocks/CU, MfmaUtil 15.7%) -- matches the guide's "128-tile 8-phase is
// null" quadrant; pipeline depth is not the lever at this tile size.
// Counted-vmcnt ring: stage g+1 before compute g, vmcnt(4), never 0 in loop.
// Content swizzle s(row) = (row + (row>>2)) & 3; staging source granule
// (lane&3)^s; read slot l4^s; s invariant under row+16 / row+64.
#define TM 128
#define TN 128
#define BK 32

__global__ __launch_bounds__(256, 4)
void gemm_softplus(const unsigned short* __restrict__ Ab,
                   const unsigned short* __restrict__ Wb,
                   const float* __restrict__ bias,
                   unsigned* __restrict__ QR) {
    __shared__ unsigned short As[2][4096];   // 2 slots x (128 rows x 32 bf16) = 16 KB
    __shared__ unsigned short Bs[2][4096];   // 16 KB   (total 32 KB)

    // XCD-chunked swizzle: 2048 blocks = 8 XCD * 256; the 8 blocks sharing an
    // A strip land on ONE XCD (measured: FETCH 265 -> 22 MB).
    const int bid     = blockIdx.x;
    const int logical = (bid & 7) * 256 + (bid >> 3);
    const int bm = logical >> 3;     // 0..255
    const int bn = logical & 7;      // 0..7

    const int t    = threadIdx.x;
    const int wave = t >> 6;
    const int lane = t & 63;
    const int wm  = (wave >> 1) * 64;
    const int wn  = (wave & 1) * 64;
    const int l15 = lane & 15;
    const int l4  = lane >> 4;

    const int m0 = bm * TM;

    // ---- staging geometry (linear LDS dest, inverse-swizzled global source) ----
    const int lr2  = lane >> 2;                        // 0..15
    const int s_st = (lr2 + (lane >> 4)) & 3;
    const int sg   = ((lane & 3) ^ s_st) * 8;          // source k offset (elems)
    const int row0 = wave * 16 + lr2;                  // tile row, issue 0 (A)
    // B tile row -> W row: rows 0..31 -> q cols bn*64+0..31, 32..63 -> same +512
    // (r), 64..95 -> q +32, 96..127 -> r +32 (enables packed {q,r} epilogue).
    const int nr0 = bn * 64 + (row0 & 31) + ((row0 & 64) >> 1) + ((row0 & 32) << 4);
    const unsigned short* ag0 = Ab + (size_t)(m0 + row0) * 512 + sg;
    const unsigned short* bg0 = Wb + (size_t)nr0 * 512 + sg;
    const unsigned short* ag1 = ag0 + (size_t)64 * 512;   // issue 1: A rows +64
    const unsigned short* bg1 = bg0 + (size_t)32 * 512;   // issue 1: B cols +32
    const int sd0 = wave * 512;          // LDS dest (elems), wave-uniform
    const int sd1 = sd0 + 2048;          // issue 1: +64 rows * 32 elems

    // ---- ds_read geometry (swizzled read matches staged content) ----
    const int s_rd = (l15 + (l15 >> 2)) & 3;
    const int gsw  = (l4 ^ s_rd) * 8;
    const int aoff = (wm + l15) * 32 + gsw;   // + i*512 per fragment (compile-time)
    const int boff = (wn + l15) * 32 + gsw;

    f32x4 acc[4][4] = {};

#define STAGE(s) do { \
    const int _sl = (s) & 1; const int _kc = (s) * BK; \
    gload_lds16(ag0 + _kc, &As[_sl][sd0]); \
    gload_lds16(ag1 + _kc, &As[_sl][sd1]); \
    gload_lds16(bg0 + _kc, &Bs[_sl][sd0]); \
    gload_lds16(bg1 + _kc, &Bs[_sl][sd1]); \
} while (0)

#define SLICE(g, VMN, DOSTG) do { \
    const unsigned short* _a = &As[(g) & 1][0]; \
    const unsigned short* _b = &Bs[(g) & 1][0]; \
    if (DOSTG) STAGE((g) + 1); \
    asm volatile("s_waitcnt vmcnt(" #VMN ")" ::: "memory"); \
    BAR(); \
    short8 af[4], bf[4]; \
    _Pragma("unroll") for (int i = 0; i < 4; ++i) { \
        af[i] = *(const short8*)(_a + aoff + i * 512); \
        bf[i] = *(const short8*)(_b + boff + i * 512); \
    } \
    __builtin_amdgcn_s_setprio(1); \
    _Pragma("unroll") for (int i = 0; i < 4; ++i) \
    _Pragma("unroll") for (int j = 0; j < 4; ++j) \
        acc[i][j] = __builtin_amdgcn_mfma_f32_16x16x32_bf16(af[i], bf[j], acc[i][j], 0, 0, 0); \
    __builtin_amdgcn_s_setprio(0); \
    BAR(); \
} while (0)

    STAGE(0);                                   // 4 loads in flight
    for (int g = 0; g < 15; ++g) {
        SLICE(g, 4, 1);                         // stage g+1; wait slice g only
    }
    SLICE(15, 0, 0);                            // tail: full drain is free

#undef SLICE
#undef STAGE

    // epilogue (rounds 1/4/6 verified): bias + softplus, packed {q,r} 4B stores
#pragma unroll
    for (int j = 0; j < 2; ++j) {
        const int h  = bn * 64 + (wn >> 1) + j * 16 + l15;  // 0..511
        const float bq = bias[h];
        const float br = bias[h + 512];
#pragma unroll
        for (int i = 0; i < 4; ++i) {
            const int mb = m0 + wm + i * 16 + l4 * 4;
#pragma unroll
            for (int r = 0; r < 4; ++r) {
                const float qv = softplus_f(acc[i][j][r] + bq);
                const float rv = softplus_f(acc[i][j + 2][r] + br);
                QR[(size_t)(mb + r) * 512 + h] = pk2bf(qv, rv);
            }
        }
    }
}

// ---------- Pass 3: chunked Kalman scan (unchanged from rounds 4-7) ----------
// 32 chunks of 128 steps, 64-step warm-up. 1 h-column/thread, 8-buffer
// rotation, prefetch depth 4 groups. ng in {16,24} -> unguarded COMP.
#define CHUNK 128
#define WARM 64

__global__ __launch_bounds__(256, 2)
void kalman_scan(const float* __restrict__ z,
                 const unsigned* __restrict__ QR,
                 float* __restrict__ out) {
    const int t     = threadIdx.x;
    const int hb    = blockIdx.x & 1;
    const int b     = (blockIdx.x >> 1) & 7;
    const int chunk = blockIdx.x >> 4;          // 0..31
    const int h     = hb * 256 + t;             // 0..511
    const int s0    = chunk << 7;               // chunk*128
    const int sw    = (chunk == 0) ? 0 : (s0 - WARM);
    const size_t base = ((size_t)(b * S_ + sw)) * 512 + h;

    const float*    zp  = z + base;             // stride 512 floats / step
    const unsigned* qrp = (const unsigned*)QR + base;
    float*          op  = out + base;

    const int ng    = ((s0 + CHUNK) - sw) >> 3;   // 16 (chunk 0) or 24
    const int skipg = (s0 - sw) >> 3;             // 0 or 8

    float    Z0[8], Z1[8], Z2[8], Z3[8], Z4[8], Z5[8], Z6[8], Z7[8];
    unsigned Q0[8], Q1[8], Q2[8], Q3[8], Q4[8], Q5[8], Q6[8], Q7[8];

#define LOADG(g, Zb, Qb) { const int _o = (g) * 8;                          \
    _Pragma("unroll") for (int u = 0; u < 8; ++u) {                         \
        Zb[u] = zp[(size_t)(_o + u) * 512]; Qb[u] = qrp[(size_t)(_o + u) * 512]; } }

#define COMP(g, Zb, Qb) { const int _o = (g) * 8; const bool _st = (g) >= skipg; \
    _Pragma("unroll") for (int u = 0; u < 8; ++u) {                         \
        const float q  = bf2f(Qb[u] & 0xffffu);                             \
        const float r  = bf2f(Qb[u] >> 16);                                 \
        const float Pp = P + q, rr = r + 1e-6f;                             \
        const float K  = Pp * __builtin_amdgcn_rcpf(Pp + rr);               \
        state = fmaf(K, Zb[u] - state, state); P = rr * K;                  \
        if (_st) op[(size_t)(_o + u) * 512] = state; } }

    LOADG(0, Z0, Q0); LOADG(1, Z1, Q1); LOADG(2, Z2, Q2); LOADG(3, Z3, Q3);

    float state = Z0[0];   // state init = z[sw]
    float P = 0.1f;

    for (int g = 0; g < ng; g += 8) {
        if (g + 4  < ng) LOADG(g + 4,  Z4, Q4); COMP(g,     Z0, Q0);
        if (g + 5  < ng) LOADG(g + 5,  Z5, Q5); COMP(g + 1, Z1, Q1);
        if (g + 6  < ng) LOADG(g + 6,  Z6, Q6); COMP(g + 2, Z2, Q2);
        if (g + 7  < ng) LOADG(g + 7,  Z7, Q7); COMP(g + 3, Z3, Q3);
        if (g + 8  < ng) LOADG(g + 8,  Z0, Q0); COMP(g + 4, Z4, Q4);
        if (g + 9  < ng) LOADG(g + 9,  Z1, Q1); COMP(g + 5, Z5, Q5);
        if (g + 10 < ng) LOADG(g + 10, Z2, Q2); COMP(g + 6, Z6, Q6);
        if (g + 11 < ng) LOADG(g + 11, Z3, Q3); COMP(g + 7, Z7, Q7);
    }
#undef LOADG
#undef COMP
}

extern "C" void kernel_launch(void* const* d_in, const int* in_sizes, int n_in,
                              void* d_out, int out_size, void* d_ws, size_t ws_size,
                              hipStream_t stream) {
    const float* lstm = (const float*)d_in[0];   // (8,4096,512) fp32
    const float* Wm   = (const float*)d_in[1];   // (1024,512)  fp32
    const float* bias = (const float*)d_in[2];   // (1024,)     fp32

    unsigned* QRw = (unsigned*)d_ws;             // packed {q,r} bf16x2, 64 MB

    // d_out (64 MB) is dead until the scan writes it -> bf16 scratch:
    // Ab = 32 MB at offset 0, Wb = 1 MB at offset 32 MB (contiguous -> one
    // flat uint2 destination for the convert kernel).
    unsigned short* Abf = (unsigned short*)d_out;
    unsigned short* Wbf = (unsigned short*)((char*)d_out + (32u << 20));

    hipLaunchKernelGGL(convert_bf16, dim3(2048), dim3(256), 0, stream,
                       lstm, Wm, (uint2*)Abf);

    // 256 M-tiles x 8 N-tiles = 2048 blocks of 256 threads (4 blocks/CU)
    hipLaunchKernelGGL(gemm_softplus, dim3(2048), dim3(256), 0, stream,
                       Abf, Wbf, bias, QRw);

    // 2 h-halves * 8 batches * 32 chunks = 512 blocks of 256 threads (2/CU)
    hipLaunchKernelGGL(kalman_scan, dim3(512), dim3(256), 0, stream,
                       lstm, QRw, (float*)d_out);
}